// Round 5
// baseline (6326.052 us; speedup 1.0000x reference)
//
#include <hip/hip_runtime.h>
#include <cstdint>
#include <cstddef>

#define N_NEU 2048
#define B_SZ  256
#define D_IN  1024
#define T_STEPS 64

typedef _Float16 f16x8 __attribute__((ext_vector_type(8)));
typedef float    f32x4 __attribute__((ext_vector_type(4)));

#define MFMA16(a, b, c) __builtin_amdgcn_mfma_f32_16x16x32_f16((a), (b), (c), 0, 0, 0)

// ---------------- ws layout (bytes) ----------------
// Wh    [2048][2048] f16 @ 0      (8 MB)
// Wl    [2048][2048] f16 @ 8 MB   (8 MB)
// Iext  [256][2048]  f32 @ 16 MB  (2 MB)
// S0    [256][2048]  f16 @ 18 MB  (1 MB)
// S1    [256][2048]  f16 @ 19 MB  (1 MB)
// counters u32[128]      @ 20 MB

// Split W_eff = adj*mask into f16 hi + f16 lo' (w ~= hi + lo'/4096, err ~2^-22). Round-1 proven.
__global__ __launch_bounds__(256) void k_wsplit(const float* __restrict__ adj,
                                                const float* __restrict__ mask,
                                                _Float16* __restrict__ Wh,
                                                _Float16* __restrict__ Wl,
                                                unsigned* __restrict__ counters) {
  if (blockIdx.x == 0 && threadIdx.x < 128) counters[threadIdx.x] = 0u;
  int i = blockIdx.x * blockDim.x + threadIdx.x;
  const int total = N_NEU * N_NEU;
  for (; i < total; i += gridDim.x * blockDim.x) {
    float w = adj[i] * mask[i];
    _Float16 h = (_Float16)w;
    Wh[i] = h;
    Wl[i] = (_Float16)((w - (float)h) * 4096.0f);
  }
}

// I_ext = ext @ W_in^T + b_in, plain fp32. Round-1 verbatim (proven absmax 0.0).
__global__ __launch_bounds__(256) void k_iext(const float* __restrict__ ext,
                                              const float* __restrict__ Win,
                                              const float* __restrict__ bin,
                                              float* __restrict__ Iext) {
  __shared__ float At[32][68];
  __shared__ float Bt[32][68];
  const int tid = threadIdx.x;
  const int b0 = (blockIdx.x & 3) * 64;
  const int n0 = (blockIdx.x >> 2) * 64;
  const int tx = tid & 15, ty = tid >> 4;
  float acc[4][4] = {};
  for (int kt = 0; kt < D_IN / 32; ++kt) {
    const int k0 = kt * 32;
#pragma unroll
    for (int i = 0; i < 8; ++i) {
      int e = tid + i * 256;
      int kk = e & 31, row = e >> 5;
      At[kk][row] = ext[(size_t)(b0 + row) * D_IN + k0 + kk];
      Bt[kk][row] = Win[(size_t)(n0 + row) * D_IN + k0 + kk];
    }
    __syncthreads();
    for (int kk = 0; kk < 32; ++kk) {
      f32x4 a = *(const f32x4*)&At[kk][ty * 4];
      f32x4 b = *(const f32x4*)&Bt[kk][tx * 4];
#pragma unroll
      for (int i = 0; i < 4; ++i)
#pragma unroll
        for (int j = 0; j < 4; ++j) acc[i][j] += a[i] * b[j];
    }
    __syncthreads();
  }
#pragma unroll
  for (int i = 0; i < 4; ++i)
#pragma unroll
    for (int j = 0; j < 4; ++j)
      Iext[(size_t)(b0 + ty * 4 + i) * N_NEU + n0 + tx * 4 + j] = acc[i][j] + bin[n0 + tx * 4 + j];
}

// Split-K tree reduction over 8 waves via LDS. red: float[4][32][64], XOR-swizzled rows.
__device__ inline void reduce_tree(float (&outv)[4], const f32x4 (&c)[4][2],
                                   float* red, int tid) {
  const int lane = tid & 63, wv = tid >> 6;
  const int cb = lane & 15, rq = (lane >> 4) << 2;
  if (wv >= 4) {
    const int p = wv - 4;
#pragma unroll
    for (int mt = 0; mt < 4; ++mt)
#pragma unroll
      for (int nt = 0; nt < 2; ++nt) {
        const int col = nt * 16 + cb;
        const int r0 = (mt * 16 + rq) ^ ((col & 7) << 2);
        *(f32x4*)(red + (p * 32 + col) * 64 + r0) = c[mt][nt];
      }
  }
  __syncthreads();
  if (wv < 4) {
#pragma unroll
    for (int mt = 0; mt < 4; ++mt)
#pragma unroll
      for (int nt = 0; nt < 2; ++nt) {
        const int col = nt * 16 + cb;
        const int r0 = (mt * 16 + rq) ^ ((col & 7) << 2);
        float* p2 = red + (wv * 32 + col) * 64 + r0;
        f32x4 o = *(const f32x4*)p2;
        o += c[mt][nt];
        *(f32x4*)p2 = o;
      }
  }
  __syncthreads();
#pragma unroll
  for (int j = 0; j < 4; ++j) {
    const int o = j * 512 + tid;
    const int row = o >> 5, col = o & 31;
    const int rs = row ^ ((col & 7) << 2);
    float s = 0.0f;
#pragma unroll
    for (int p = 0; p < 4; ++p) s += red[(p * 32 + col) * 64 + rs];
    outv[j] = s;
  }
}

// Persistent fused LIF kernel. 256 blocks x 512 thr (1 block/CU).
// Block (bg, ns): batch rows bg*64..+64, neuron cols ns*32..+32.
// 8 waves split K (2048/8 = 256 each). Wh frags resident in VGPRs; Wl streamed;
// spikes via f16 S0/S1 ping-pong (round-1 proven semantics).
__global__ __launch_bounds__(512, 2) void k_fused2(
    const _Float16* __restrict__ Wh, const _Float16* __restrict__ Wl,
    const float* __restrict__ Iext, _Float16* __restrict__ S0,
    _Float16* __restrict__ S1, unsigned* __restrict__ counters,
    float* __restrict__ out) {
  __shared__ float red[4 * 32 * 64];

  const int tid = threadIdx.x;
  const int lane = tid & 63;
  const int kw = tid >> 6;       // wave id = split-K index 0..7
  const int l15 = lane & 15;
  const int klo = lane >> 4;     // 0..3
  const int bg = blockIdx.x >> 6;   // 0..3 batch group
  const int ns = blockIdx.x & 63;   // 0..63 neuron slice
  const int n0 = ns * 32;
  const float inv4096 = 1.0f / 4096.0f;
  const f32x4 z4 = {0.f, 0.f, 0.f, 0.f};

  // ---------- per-thread Iext (proven fp32 values from k_iext) ----------
  float Iext_r[4];
#pragma unroll
  for (int j = 0; j < 4; ++j)
    Iext_r[j] = Iext[(size_t)(bg * 64 + j * 16 + (tid >> 5)) * N_NEU + n0 + (tid & 31)];

  // ---------- resident Wh fragments; base for streamed Wl ----------
  const _Float16* whb = Wh + (size_t)(n0 + l15) * N_NEU + kw * 256 + klo * 8;
  const _Float16* wlb = Wl + (size_t)(n0 + l15) * N_NEU + kw * 256 + klo * 8;
  f16x8 whf[2][8];
#pragma unroll
  for (int nt = 0; nt < 2; ++nt)
#pragma unroll
    for (int kcl = 0; kcl < 8; ++kcl)
      whf[nt][kcl] = *(const f16x8*)(whb + nt * 16 * N_NEU + kcl * 32);

  unsigned* bar = counters + bg * 32;

  float V[4] = {0.f, 0.f, 0.f, 0.f};
  unsigned cnt[4] = {0u, 0u, 0u, 0u};

  for (int t = 0; t < T_STEPS; ++t) {
    float cI[4];
    if (t == 0) {
      cI[0] = cI[1] = cI[2] = cI[3] = 0.0f;
    } else {
      const _Float16* Sin = (t & 1) ? S1 : S0;
      const _Float16* sb = Sin + (size_t)(bg * 64 + l15) * N_NEU + kw * 256 + klo * 8;
      f32x4 acch[4][2], accl[4][2];
#pragma unroll
      for (int mt = 0; mt < 4; ++mt)
#pragma unroll
        for (int nt = 0; nt < 2; ++nt) { acch[mt][nt] = z4; accl[mt][nt] = z4; }

#pragma unroll
      for (int kcl = 0; kcl < 8; ++kcl) {
        const f16x8 w0 = *(const f16x8*)(wlb + kcl * 32);
        const f16x8 w1 = *(const f16x8*)(wlb + 16 * N_NEU + kcl * 32);
#pragma unroll
        for (int mt = 0; mt < 4; ++mt) {
          const f16x8 a = *(const f16x8*)(sb + (size_t)mt * 16 * N_NEU + kcl * 32);
          acch[mt][0] = MFMA16(a, whf[0][kcl], acch[mt][0]);
          accl[mt][0] = MFMA16(a, w0, accl[mt][0]);
          acch[mt][1] = MFMA16(a, whf[1][kcl], acch[mt][1]);
          accl[mt][1] = MFMA16(a, w1, accl[mt][1]);
        }
      }
      f32x4 cb[4][2];
#pragma unroll
      for (int mt = 0; mt < 4; ++mt)
#pragma unroll
        for (int nt = 0; nt < 2; ++nt) cb[mt][nt] = acch[mt][nt] + accl[mt][nt] * inv4096;
      reduce_tree(cI, cb, red, tid);
    }

    // ---------- fused LIF epilogue (state in registers) ----------
    _Float16* Sout = (t & 1) ? S0 : S1;  // write buffer (t+1)&1
#pragma unroll
    for (int j = 0; j < 4; ++j) {
      float I = cI[j] + Iext_r[j];
      float v = 0.9f * V[j] + I;
      bool sp = (v - 1.0f) >= 0.0f;
      V[j] = sp ? 0.0f : v;
      cnt[j] += sp ? 1u : 0u;
      if (t < T_STEPS - 1)
        Sout[(size_t)(bg * 64 + j * 16 + (tid >> 5)) * N_NEU + n0 + (tid & 31)] =
            sp ? (_Float16)1.0f : (_Float16)0.0f;
    }

    // ---------- group barrier (64 blocks sharing bg), monotonic counter ----------
    if (t < T_STEPS - 1) {
      __threadfence();
      __syncthreads();
      if (tid == 0) {
        __hip_atomic_fetch_add(bar, 1u, __ATOMIC_RELEASE, __HIP_MEMORY_SCOPE_AGENT);
        const unsigned tgt = 64u * (unsigned)(t + 1);
        while (__hip_atomic_load(bar, __ATOMIC_ACQUIRE, __HIP_MEMORY_SCOPE_AGENT) < tgt)
          __builtin_amdgcn_s_sleep(1);
      }
      __syncthreads();
      __threadfence();  // paranoid acquire: force L1/L2 invalidate on every wave
    }
  }

  // ---------- write firing rates ----------
#pragma unroll
  for (int j = 0; j < 4; ++j) {
    const int row = j * 16 + (tid >> 5);
    out[(size_t)(bg * 64 + row) * N_NEU + n0 + (tid & 31)] = (float)cnt[j] * 0.015625f;
  }
}

extern "C" void kernel_launch(void* const* d_in, const int* in_sizes, int n_in,
                              void* d_out, int out_size, void* d_ws, size_t ws_size,
                              hipStream_t stream) {
  (void)in_sizes; (void)n_in; (void)out_size; (void)ws_size;
  const float* ext  = (const float*)d_in[0];
  const float* Win  = (const float*)d_in[1];
  const float* bin  = (const float*)d_in[2];
  const float* adj  = (const float*)d_in[3];
  const float* mask = (const float*)d_in[4];
  unsigned char* ws = (unsigned char*)d_ws;

  _Float16* Wh   = (_Float16*)(ws);
  _Float16* Wl   = (_Float16*)(ws + (size_t)(8u << 20));
  float*    Iext = (float*)   (ws + (size_t)(16u << 20));
  _Float16* S0   = (_Float16*)(ws + (size_t)(18u << 20));
  _Float16* S1   = (_Float16*)(ws + (size_t)(19u << 20));
  unsigned* counters = (unsigned*)(ws + (size_t)(20u << 20));
  float* out = (float*)d_out;

  hipLaunchKernelGGL(k_wsplit, dim3(2048), dim3(256), 0, stream, adj, mask, Wh, Wl, counters);
  hipLaunchKernelGGL(k_iext,   dim3(128),  dim3(256), 0, stream, ext, Win, bin, Iext);
  hipLaunchKernelGGL(k_fused2, dim3(256),  dim3(512), 0, stream,
                     Wh, Wl, Iext, S0, S1, counters, out);
}

// Round 6
// 835.657 us; speedup vs baseline: 7.5702x; 7.5702x over previous
//
#include <hip/hip_runtime.h>
#include <cstdint>
#include <cstddef>

#define N_NEU 2048
#define B_SZ  256
#define D_IN  1024
#define T_STEPS 64

typedef _Float16 f16x8 __attribute__((ext_vector_type(8)));
typedef float    f32x4 __attribute__((ext_vector_type(4)));
typedef unsigned u32x4 __attribute__((ext_vector_type(4)));

#define MFMA16(a, b, c) __builtin_amdgcn_mfma_f32_16x16x32_f16((a), (b), (c), 0, 0, 0)

// ---------------- ws layout (bytes) ----------------
// Wh     [2048][2048] f16      @ 0       (8 MB)
// Wl     [2048][2048] f16      @ 8 MB    (8 MB)
// Iext   [256][2048]  f32      @ 16 MB   (2 MB)
// bitmap u32[2][256][64]       @ 18 MB   (128 KB)  spike bits: [buf][b][n/32], bit n%32
// flags  u32[512]              @ 18 MB + 128 KB    per-block epoch flags (bg*64 + ns)

// 8 bits -> 8 f16 (0.0 / 1.0)
__device__ inline f16x8 expand8(unsigned b) {
  u32x4 t;
  t[0] = ((b & 1u)   ? 0x3C00u : 0u) | ((b & 2u)   ? 0x3C000000u : 0u);
  t[1] = ((b & 4u)   ? 0x3C00u : 0u) | ((b & 8u)   ? 0x3C000000u : 0u);
  t[2] = ((b & 16u)  ? 0x3C00u : 0u) | ((b & 32u)  ? 0x3C000000u : 0u);
  t[3] = ((b & 64u)  ? 0x3C00u : 0u) | ((b & 128u) ? 0x3C000000u : 0u);
  return __builtin_bit_cast(f16x8, t);
}

// Split W_eff = adj*mask into f16 hi + f16 lo' (w ~= hi + lo'/4096, err ~2^-22). Proven r1/r5.
__global__ __launch_bounds__(256) void k_wsplit(const float* __restrict__ adj,
                                                const float* __restrict__ mask,
                                                _Float16* __restrict__ Wh,
                                                _Float16* __restrict__ Wl,
                                                unsigned* __restrict__ flags) {
  if (blockIdx.x == 0) { flags[threadIdx.x] = 0u; flags[threadIdx.x + 256] = 0u; }
  int i = blockIdx.x * blockDim.x + threadIdx.x;
  const int total = N_NEU * N_NEU;
  for (; i < total; i += gridDim.x * blockDim.x) {
    float w = adj[i] * mask[i];
    _Float16 h = (_Float16)w;
    Wh[i] = h;
    Wl[i] = (_Float16)((w - (float)h) * 4096.0f);
  }
}

// I_ext = ext @ W_in^T + b_in, plain fp32. Round-1/5 verbatim (proven absmax 0.0).
__global__ __launch_bounds__(256) void k_iext(const float* __restrict__ ext,
                                              const float* __restrict__ Win,
                                              const float* __restrict__ bin,
                                              float* __restrict__ Iext) {
  __shared__ float At[32][68];
  __shared__ float Bt[32][68];
  const int tid = threadIdx.x;
  const int b0 = (blockIdx.x & 3) * 64;
  const int n0 = (blockIdx.x >> 2) * 64;
  const int tx = tid & 15, ty = tid >> 4;
  float acc[4][4] = {};
  for (int kt = 0; kt < D_IN / 32; ++kt) {
    const int k0 = kt * 32;
#pragma unroll
    for (int i = 0; i < 8; ++i) {
      int e = tid + i * 256;
      int kk = e & 31, row = e >> 5;
      At[kk][row] = ext[(size_t)(b0 + row) * D_IN + k0 + kk];
      Bt[kk][row] = Win[(size_t)(n0 + row) * D_IN + k0 + kk];
    }
    __syncthreads();
    for (int kk = 0; kk < 32; ++kk) {
      f32x4 a = *(const f32x4*)&At[kk][ty * 4];
      f32x4 b = *(const f32x4*)&Bt[kk][tx * 4];
#pragma unroll
      for (int i = 0; i < 4; ++i)
#pragma unroll
        for (int j = 0; j < 4; ++j) acc[i][j] += a[i] * b[j];
    }
    __syncthreads();
  }
#pragma unroll
  for (int i = 0; i < 4; ++i)
#pragma unroll
    for (int j = 0; j < 4; ++j)
      Iext[(size_t)(b0 + ty * 4 + i) * N_NEU + n0 + tx * 4 + j] = acc[i][j] + bin[n0 + tx * 4 + j];
}

// Split-K tree reduction over 8 waves via LDS. red: float[4][32][64], XOR-swizzled rows. Proven r5.
__device__ inline void reduce_tree(float (&outv)[4], const f32x4 (&c)[4][2],
                                   float* red, int tid) {
  const int lane = tid & 63, wv = tid >> 6;
  const int cb = lane & 15, rq = (lane >> 4) << 2;
  if (wv >= 4) {
    const int p = wv - 4;
#pragma unroll
    for (int mt = 0; mt < 4; ++mt)
#pragma unroll
      for (int nt = 0; nt < 2; ++nt) {
        const int col = nt * 16 + cb;
        const int r0 = (mt * 16 + rq) ^ ((col & 7) << 2);
        *(f32x4*)(red + (p * 32 + col) * 64 + r0) = c[mt][nt];
      }
  }
  __syncthreads();
  if (wv < 4) {
#pragma unroll
    for (int mt = 0; mt < 4; ++mt)
#pragma unroll
      for (int nt = 0; nt < 2; ++nt) {
        const int col = nt * 16 + cb;
        const int r0 = (mt * 16 + rq) ^ ((col & 7) << 2);
        float* p2 = red + (wv * 32 + col) * 64 + r0;
        f32x4 o = *(const f32x4*)p2;
        o += c[mt][nt];
        *(f32x4*)p2 = o;
      }
  }
  __syncthreads();
#pragma unroll
  for (int j = 0; j < 4; ++j) {
    const int o = j * 512 + tid;
    const int row = o >> 5, col = o & 31;
    const int rs = row ^ ((col & 7) << 2);
    float s = 0.0f;
#pragma unroll
    for (int p = 0; p < 4; ++p) s += red[(p * 32 + col) * 64 + rs];
    outv[j] = s;
  }
}

// Persistent fused LIF kernel. 256 blocks x 512 thr (1 block/CU, co-residency guaranteed).
// Block (bg, ns): batch rows bg*64..+64, neuron cols ns*32..+32. 8 waves split K.
// Wh resident in VGPRs; Wl streamed (read-only, per-XCD-L2-resident, ~1 MB/XCD).
// Spikes: double-buffered bitmap, ALL cross-block traffic via relaxed AGENT atomics
// (sc0/sc1 -> LLC-coherent, no L1/L2 staleness, no cache-maintenance fences).
__global__ __launch_bounds__(512, 2) void k_fused3(
    const _Float16* __restrict__ Wh, const _Float16* __restrict__ Wl,
    const float* __restrict__ Iext, unsigned* __restrict__ bitmap,
    unsigned* __restrict__ flags, float* __restrict__ out) {
  __shared__ float red[4 * 32 * 64];

  const int tid = threadIdx.x;
  const int lane = tid & 63;
  const int kw = tid >> 6;       // wave id = split-K index 0..7
  const int l15 = lane & 15;
  const int klo = lane >> 4;     // 0..3
  const int sh = klo * 8;
  const int bg = blockIdx.x >> 6;   // 0..3 batch group
  const int ns = blockIdx.x & 63;   // 0..63 neuron slice
  const int n0 = ns * 32;
  const float inv4096 = 1.0f / 4096.0f;
  const f32x4 z4 = {0.f, 0.f, 0.f, 0.f};

  // ---------- per-thread Iext (proven fp32 values from k_iext) ----------
  float Iext_r[4];
#pragma unroll
  for (int j = 0; j < 4; ++j)
    Iext_r[j] = Iext[(size_t)(bg * 64 + j * 16 + (tid >> 5)) * N_NEU + n0 + (tid & 31)];

  // ---------- resident Wh fragments; base for streamed Wl ----------
  const _Float16* whb = Wh + (size_t)(n0 + l15) * N_NEU + kw * 256 + klo * 8;
  const _Float16* wlb = Wl + (size_t)(n0 + l15) * N_NEU + kw * 256 + klo * 8;
  f16x8 whf[2][8];
#pragma unroll
  for (int nt = 0; nt < 2; ++nt)
#pragma unroll
    for (int kcl = 0; kcl < 8; ++kcl)
      whf[nt][kcl] = *(const f16x8*)(whb + nt * 16 * N_NEU + kcl * 32);

  float V[4] = {0.f, 0.f, 0.f, 0.f};
  unsigned cnt[4] = {0u, 0u, 0u, 0u};

  for (int t = 0; t < T_STEPS; ++t) {
    float cI[4];
    if (t == 0) {
      cI[0] = cI[1] = cI[2] = cI[3] = 0.0f;
    } else {
      // spike bitmap rows for this wave's K-span: words [row][kw*8 .. kw*8+7], LLC-coherent loads
      const size_t pbase = ((size_t)(t & 1) * 256 + bg * 64) * 64;
      unsigned long long q[4][4];
#pragma unroll
      for (int mt = 0; mt < 4; ++mt) {
        const unsigned long long* qp =
            (const unsigned long long*)(bitmap + pbase + (size_t)(mt * 16 + l15) * 64 + kw * 8);
#pragma unroll
        for (int i = 0; i < 4; ++i)
          q[mt][i] = __hip_atomic_load(qp + i, __ATOMIC_RELAXED, __HIP_MEMORY_SCOPE_AGENT);
      }

      f32x4 acch[4][2], accl[4][2];
#pragma unroll
      for (int mt = 0; mt < 4; ++mt)
#pragma unroll
        for (int nt = 0; nt < 2; ++nt) { acch[mt][nt] = z4; accl[mt][nt] = z4; }

#pragma unroll
      for (int kcl = 0; kcl < 8; ++kcl) {
        const f16x8 w0 = *(const f16x8*)(wlb + kcl * 32);
        const f16x8 w1 = *(const f16x8*)(wlb + 16 * N_NEU + kcl * 32);
#pragma unroll
        for (int mt = 0; mt < 4; ++mt) {
          const unsigned word = (unsigned)(q[mt][kcl >> 1] >> (32 * (kcl & 1)));
          const f16x8 a = expand8((word >> sh) & 0xFFu);
          acch[mt][0] = MFMA16(a, whf[0][kcl], acch[mt][0]);
          accl[mt][0] = MFMA16(a, w0, accl[mt][0]);
          acch[mt][1] = MFMA16(a, whf[1][kcl], acch[mt][1]);
          accl[mt][1] = MFMA16(a, w1, accl[mt][1]);
        }
      }
      f32x4 cb[4][2];
#pragma unroll
      for (int mt = 0; mt < 4; ++mt)
#pragma unroll
        for (int nt = 0; nt < 2; ++nt) cb[mt][nt] = acch[mt][nt] + accl[mt][nt] * inv4096;
      reduce_tree(cI, cb, red, tid);
    }

    // ---------- fused LIF epilogue (state in registers); spikes -> bitmap[(t+1)&1] ----------
    const size_t wbase = ((size_t)((t + 1) & 1) * 256 + bg * 64) * 64;
#pragma unroll
    for (int j = 0; j < 4; ++j) {
      float I = cI[j] + Iext_r[j];
      float v = 0.9f * V[j] + I;
      bool sp = (v - 1.0f) >= 0.0f;
      V[j] = sp ? 0.0f : v;
      cnt[j] += sp ? 1u : 0u;
      if (t < T_STEPS - 1) {
        unsigned long long ba = __ballot(sp);
        const int row = j * 16 + 2 * kw;   // lanes 0-31 hold batch row 'row', lanes 32-63 'row+1'
        if (lane == 0)
          __hip_atomic_store(bitmap + wbase + (size_t)row * 64 + ns, (unsigned)ba,
                             __ATOMIC_RELAXED, __HIP_MEMORY_SCOPE_AGENT);
        else if (lane == 32)
          __hip_atomic_store(bitmap + wbase + (size_t)(row + 1) * 64 + ns, (unsigned)(ba >> 32),
                             __ATOMIC_RELAXED, __HIP_MEMORY_SCOPE_AGENT);
      }
    }

    // ---------- group barrier: per-block epoch flags, lane-parallel poll, no fences ----------
    if (t < T_STEPS - 1) {
      asm volatile("s_waitcnt vmcnt(0)" ::: "memory");  // spike stores acked at LLC
      __syncthreads();                                  // all waves' stores drained
      if (tid == 0)
        __hip_atomic_store(&flags[bg * 64 + ns], (unsigned)(t + 1),
                           __ATOMIC_RELAXED, __HIP_MEMORY_SCOPE_AGENT);
      if (kw == 0) {
        const unsigned tgt = (unsigned)(t + 1);
        while (true) {
          unsigned v = __hip_atomic_load(&flags[bg * 64 + lane],
                                         __ATOMIC_RELAXED, __HIP_MEMORY_SCOPE_AGENT);
          if (__all(v >= tgt)) break;
          __builtin_amdgcn_s_sleep(8);
        }
      }
      __syncthreads();
    }
  }

  // ---------- write firing rates ----------
#pragma unroll
  for (int j = 0; j < 4; ++j) {
    const int row = j * 16 + (tid >> 5);
    out[(size_t)(bg * 64 + row) * N_NEU + n0 + (tid & 31)] = (float)cnt[j] * 0.015625f;
  }
}

extern "C" void kernel_launch(void* const* d_in, const int* in_sizes, int n_in,
                              void* d_out, int out_size, void* d_ws, size_t ws_size,
                              hipStream_t stream) {
  (void)in_sizes; (void)n_in; (void)out_size; (void)ws_size;
  const float* ext  = (const float*)d_in[0];
  const float* Win  = (const float*)d_in[1];
  const float* bin  = (const float*)d_in[2];
  const float* adj  = (const float*)d_in[3];
  const float* mask = (const float*)d_in[4];
  unsigned char* ws = (unsigned char*)d_ws;

  _Float16* Wh     = (_Float16*)(ws);
  _Float16* Wl     = (_Float16*)(ws + (size_t)(8u << 20));
  float*    Iext   = (float*)   (ws + (size_t)(16u << 20));
  unsigned* bitmap = (unsigned*)(ws + (size_t)(18u << 20));
  unsigned* flags  = (unsigned*)(ws + (size_t)(18u << 20) + 131072u);
  float* out = (float*)d_out;

  hipLaunchKernelGGL(k_wsplit, dim3(2048), dim3(256), 0, stream, adj, mask, Wh, Wl, flags);
  hipLaunchKernelGGL(k_iext,   dim3(128),  dim3(256), 0, stream, ext, Win, bin, Iext);
  hipLaunchKernelGGL(k_fused3, dim3(256),  dim3(512), 0, stream,
                     Wh, Wl, Iext, bitmap, flags, out);
}

// Round 7
// 639.937 us; speedup vs baseline: 9.8854x; 1.3058x over previous
//
#include <hip/hip_runtime.h>
#include <cstdint>
#include <cstddef>

#define N_NEU 2048
#define B_SZ  256
#define D_IN  1024
#define T_STEPS 64

typedef _Float16 f16x8 __attribute__((ext_vector_type(8)));
typedef float    f32x4 __attribute__((ext_vector_type(4)));
typedef unsigned u32x4 __attribute__((ext_vector_type(4)));

#define MFMA16(a, b, c) __builtin_amdgcn_mfma_f32_16x16x32_f16((a), (b), (c), 0, 0, 0)

// ---------------- ws layout (bytes) ----------------
// Wh     [2048][2048] f16      @ 0       (8 MB)
// Wl     [2048][2048] f16      @ 8 MB    (8 MB)
// Iext   [256][2048]  f32      @ 16 MB   (2 MB)
// bitmap u32[2][256][64]       @ 18 MB   (128 KB)  spike bits: [buf][b][n/32], bit n%32
// flags  u32[512]              @ 18 MB + 128 KB    per-block epoch flags (bg*64 + ns)

// 8 bits -> 8 f16 (0.0 / 1.0)
__device__ inline f16x8 expand8(unsigned b) {
  u32x4 t;
  t[0] = ((b & 1u)   ? 0x3C00u : 0u) | ((b & 2u)   ? 0x3C000000u : 0u);
  t[1] = ((b & 4u)   ? 0x3C00u : 0u) | ((b & 8u)   ? 0x3C000000u : 0u);
  t[2] = ((b & 16u)  ? 0x3C00u : 0u) | ((b & 32u)  ? 0x3C000000u : 0u);
  t[3] = ((b & 64u)  ? 0x3C00u : 0u) | ((b & 128u) ? 0x3C000000u : 0u);
  return __builtin_bit_cast(f16x8, t);
}

// Split W_eff = adj*mask into f16 hi + f16 lo' (w ~= hi + lo'/4096, err ~2^-22). Proven r1/r5/r6.
__global__ __launch_bounds__(256) void k_wsplit(const float* __restrict__ adj,
                                                const float* __restrict__ mask,
                                                _Float16* __restrict__ Wh,
                                                _Float16* __restrict__ Wl,
                                                unsigned* __restrict__ flags) {
  if (blockIdx.x == 0) { flags[threadIdx.x] = 0u; flags[threadIdx.x + 256] = 0u; }
  int i = blockIdx.x * blockDim.x + threadIdx.x;
  const int total = N_NEU * N_NEU;
  for (; i < total; i += gridDim.x * blockDim.x) {
    float w = adj[i] * mask[i];
    _Float16 h = (_Float16)w;
    Wh[i] = h;
    Wl[i] = (_Float16)((w - (float)h) * 4096.0f);
  }
}

// I_ext = ext @ W_in^T + b_in, plain fp32. Proven absmax 0.0 (r1/r5/r6).
__global__ __launch_bounds__(256) void k_iext(const float* __restrict__ ext,
                                              const float* __restrict__ Win,
                                              const float* __restrict__ bin,
                                              float* __restrict__ Iext) {
  __shared__ float At[32][68];
  __shared__ float Bt[32][68];
  const int tid = threadIdx.x;
  const int b0 = (blockIdx.x & 3) * 64;
  const int n0 = (blockIdx.x >> 2) * 64;
  const int tx = tid & 15, ty = tid >> 4;
  float acc[4][4] = {};
  for (int kt = 0; kt < D_IN / 32; ++kt) {
    const int k0 = kt * 32;
#pragma unroll
    for (int i = 0; i < 8; ++i) {
      int e = tid + i * 256;
      int kk = e & 31, row = e >> 5;
      At[kk][row] = ext[(size_t)(b0 + row) * D_IN + k0 + kk];
      Bt[kk][row] = Win[(size_t)(n0 + row) * D_IN + k0 + kk];
    }
    __syncthreads();
    for (int kk = 0; kk < 32; ++kk) {
      f32x4 a = *(const f32x4*)&At[kk][ty * 4];
      f32x4 b = *(const f32x4*)&Bt[kk][tx * 4];
#pragma unroll
      for (int i = 0; i < 4; ++i)
#pragma unroll
        for (int j = 0; j < 4; ++j) acc[i][j] += a[i] * b[j];
    }
    __syncthreads();
  }
#pragma unroll
  for (int i = 0; i < 4; ++i)
#pragma unroll
    for (int j = 0; j < 4; ++j)
      Iext[(size_t)(b0 + ty * 4 + i) * N_NEU + n0 + tx * 4 + j] = acc[i][j] + bin[n0 + tx * 4 + j];
}

// Split-K tree reduction over 8 waves via LDS. red: float[4][32][64], XOR-swizzled rows. Proven r5/r6.
__device__ inline void reduce_tree(float (&outv)[4], const f32x4 (&c)[4][2],
                                   float* red, int tid) {
  const int lane = tid & 63, wv = tid >> 6;
  const int cb = lane & 15, rq = (lane >> 4) << 2;
  if (wv >= 4) {
    const int p = wv - 4;
#pragma unroll
    for (int mt = 0; mt < 4; ++mt)
#pragma unroll
      for (int nt = 0; nt < 2; ++nt) {
        const int col = nt * 16 + cb;
        const int r0 = (mt * 16 + rq) ^ ((col & 7) << 2);
        *(f32x4*)(red + (p * 32 + col) * 64 + r0) = c[mt][nt];
      }
  }
  __syncthreads();
  if (wv < 4) {
#pragma unroll
    for (int mt = 0; mt < 4; ++mt)
#pragma unroll
      for (int nt = 0; nt < 2; ++nt) {
        const int col = nt * 16 + cb;
        const int r0 = (mt * 16 + rq) ^ ((col & 7) << 2);
        float* p2 = red + (wv * 32 + col) * 64 + r0;
        f32x4 o = *(const f32x4*)p2;
        o += c[mt][nt];
        *(f32x4*)p2 = o;
      }
  }
  __syncthreads();
#pragma unroll
  for (int j = 0; j < 4; ++j) {
    const int o = j * 512 + tid;
    const int row = o >> 5, col = o & 31;
    const int rs = row ^ ((col & 7) << 2);
    float s = 0.0f;
#pragma unroll
    for (int p = 0; p < 4; ++p) s += red[(p * 32 + col) * 64 + rs];
    outv[j] = s;
  }
}

// Persistent fused LIF kernel. 256 blocks x 512 thr (1 block/CU).
// Block (bg, ns): batch rows bg*64..+64, neuron cols ns*32..+32. 8 waves split K.
// BOTH Wh and Wl resident in VGPRs (K-loop is pure-register). Spike bitmap staged
// per block via coalesced LLC-atomic u64 loads into XOR-swizzled LDS.
__global__ __launch_bounds__(512, 2) void k_fused4(
    const _Float16* __restrict__ Wh, const _Float16* __restrict__ Wl,
    const float* __restrict__ Iext, unsigned* __restrict__ bitmap,
    unsigned* __restrict__ flags, float* __restrict__ out) {
  __shared__ float red[4 * 32 * 64];                 // 32 KB
  __shared__ unsigned long long bm_lds[64][32];      // 16 KB

  const int tid = threadIdx.x;
  const int lane = tid & 63;
  const int kw = tid >> 6;       // wave id = split-K index 0..7
  const int l15 = lane & 15;
  const int klo = lane >> 4;     // 0..3
  const int sh = klo * 8;
  const int bg = blockIdx.x >> 6;   // 0..3 batch group
  const int ns = blockIdx.x & 63;   // 0..63 neuron slice
  const int n0 = ns * 32;
  const float inv4096 = 1.0f / 4096.0f;
  const f32x4 z4 = {0.f, 0.f, 0.f, 0.f};

  // ---------- per-thread Iext (proven fp32 values from k_iext) ----------
  float Iext_r[4];
#pragma unroll
  for (int j = 0; j < 4; ++j)
    Iext_r[j] = Iext[(size_t)(bg * 64 + j * 16 + (tid >> 5)) * N_NEU + n0 + (tid & 31)];

  // ---------- resident Wh AND Wl fragments ----------
  const _Float16* whb = Wh + (size_t)(n0 + l15) * N_NEU + kw * 256 + klo * 8;
  const _Float16* wlb = Wl + (size_t)(n0 + l15) * N_NEU + kw * 256 + klo * 8;
  f16x8 whf[2][8], wlf[2][8];
#pragma unroll
  for (int nt = 0; nt < 2; ++nt)
#pragma unroll
    for (int kcl = 0; kcl < 8; ++kcl) {
      whf[nt][kcl] = *(const f16x8*)(whb + nt * 16 * N_NEU + kcl * 32);
      wlf[nt][kcl] = *(const f16x8*)(wlb + nt * 16 * N_NEU + kcl * 32);
    }

  float V[4] = {0.f, 0.f, 0.f, 0.f};
  unsigned cnt[4] = {0u, 0u, 0u, 0u};

  for (int t = 0; t < T_STEPS; ++t) {
    float cI[4];
    if (t == 0) {
      cI[0] = cI[1] = cI[2] = cI[3] = 0.0f;
    } else {
      // ---- stage spike bitmap (16 KB) into LDS: coalesced LLC-atomic u64 loads ----
      const unsigned long long* src =
          (const unsigned long long*)(bitmap + ((size_t)(t & 1) * 256 + bg * 64) * 64);
#pragma unroll
      for (int i = 0; i < 4; ++i) {
        const int g = i * 512 + tid;         // pair index 0..2047
        const int row = g >> 5, pr = g & 31;
        unsigned long long v =
            __hip_atomic_load(src + g, __ATOMIC_RELAXED, __HIP_MEMORY_SCOPE_AGENT);
        bm_lds[row][pr ^ (row & 31)] = v;
      }
      __syncthreads();

      f32x4 acch[4][2], accl[4][2];
#pragma unroll
      for (int mt = 0; mt < 4; ++mt)
#pragma unroll
        for (int nt = 0; nt < 2; ++nt) { acch[mt][nt] = z4; accl[mt][nt] = z4; }

#pragma unroll
      for (int mt = 0; mt < 4; ++mt) {
        const int row = mt * 16 + l15;
        unsigned long long q[4];
#pragma unroll
        for (int i = 0; i < 4; ++i) q[i] = bm_lds[row][(kw * 4 + i) ^ (row & 31)];
#pragma unroll
        for (int kcl = 0; kcl < 8; ++kcl) {
          const unsigned word = (unsigned)(q[kcl >> 1] >> (32 * (kcl & 1)));
          const f16x8 a = expand8((word >> sh) & 0xFFu);
          acch[mt][0] = MFMA16(a, whf[0][kcl], acch[mt][0]);
          accl[mt][0] = MFMA16(a, wlf[0][kcl], accl[mt][0]);
          acch[mt][1] = MFMA16(a, whf[1][kcl], acch[mt][1]);
          accl[mt][1] = MFMA16(a, wlf[1][kcl], accl[mt][1]);
        }
      }
      f32x4 cb[4][2];
#pragma unroll
      for (int mt = 0; mt < 4; ++mt)
#pragma unroll
        for (int nt = 0; nt < 2; ++nt) cb[mt][nt] = acch[mt][nt] + accl[mt][nt] * inv4096;
      __syncthreads();  // bm_lds reads done before red reuse barrier pattern below
      reduce_tree(cI, cb, red, tid);
    }

    // ---------- fused LIF epilogue (state in registers); spikes -> bitmap[(t+1)&1] ----------
    const size_t wbase = ((size_t)((t + 1) & 1) * 256 + bg * 64) * 64;
#pragma unroll
    for (int j = 0; j < 4; ++j) {
      float I = cI[j] + Iext_r[j];
      float v = 0.9f * V[j] + I;
      bool sp = (v - 1.0f) >= 0.0f;
      V[j] = sp ? 0.0f : v;
      cnt[j] += sp ? 1u : 0u;
      if (t < T_STEPS - 1) {
        unsigned long long ba = __ballot(sp);
        const int row = j * 16 + 2 * kw;   // lanes 0-31: row, lanes 32-63: row+1
        if (lane == 0)
          __hip_atomic_store(bitmap + wbase + (size_t)row * 64 + ns, (unsigned)ba,
                             __ATOMIC_RELAXED, __HIP_MEMORY_SCOPE_AGENT);
        else if (lane == 32)
          __hip_atomic_store(bitmap + wbase + (size_t)(row + 1) * 64 + ns, (unsigned)(ba >> 32),
                             __ATOMIC_RELAXED, __HIP_MEMORY_SCOPE_AGENT);
      }
    }

    // ---------- group barrier: per-block epoch flags, lane-parallel poll ----------
    if (t < T_STEPS - 1) {
      asm volatile("s_waitcnt vmcnt(0)" ::: "memory");  // spike stores acked at LLC
      __syncthreads();                                  // all waves' stores drained
      if (tid == 0)
        __hip_atomic_store(&flags[bg * 64 + ns], (unsigned)(t + 1),
                           __ATOMIC_RELAXED, __HIP_MEMORY_SCOPE_AGENT);
      if (kw == 0) {
        const unsigned tgt = (unsigned)(t + 1);
        while (true) {
          unsigned v = __hip_atomic_load(&flags[bg * 64 + lane],
                                         __ATOMIC_RELAXED, __HIP_MEMORY_SCOPE_AGENT);
          if (__all(v >= tgt)) break;
          __builtin_amdgcn_s_sleep(1);
        }
      }
      __syncthreads();
    }
  }

  // ---------- write firing rates ----------
#pragma unroll
  for (int j = 0; j < 4; ++j) {
    const int row = j * 16 + (tid >> 5);
    out[(size_t)(bg * 64 + row) * N_NEU + n0 + (tid & 31)] = (float)cnt[j] * 0.015625f;
  }
}

extern "C" void kernel_launch(void* const* d_in, const int* in_sizes, int n_in,
                              void* d_out, int out_size, void* d_ws, size_t ws_size,
                              hipStream_t stream) {
  (void)in_sizes; (void)n_in; (void)out_size; (void)ws_size;
  const float* ext  = (const float*)d_in[0];
  const float* Win  = (const float*)d_in[1];
  const float* bin  = (const float*)d_in[2];
  const float* adj  = (const float*)d_in[3];
  const float* mask = (const float*)d_in[4];
  unsigned char* ws = (unsigned char*)d_ws;

  _Float16* Wh     = (_Float16*)(ws);
  _Float16* Wl     = (_Float16*)(ws + (size_t)(8u << 20));
  float*    Iext   = (float*)   (ws + (size_t)(16u << 20));
  unsigned* bitmap = (unsigned*)(ws + (size_t)(18u << 20));
  unsigned* flags  = (unsigned*)(ws + (size_t)(18u << 20) + 131072u);
  float* out = (float*)d_out;

  hipLaunchKernelGGL(k_wsplit, dim3(2048), dim3(256), 0, stream, adj, mask, Wh, Wl, flags);
  hipLaunchKernelGGL(k_iext,   dim3(128),  dim3(256), 0, stream, ext, Win, bin, Iext);
  hipLaunchKernelGGL(k_fused4, dim3(256),  dim3(512), 0, stream,
                     Wh, Wl, Iext, bitmap, flags, out);
}